// Round 1
// 737.741 us; speedup vs baseline: 1.1086x; 1.1086x over previous
//
#include <hip/hip_runtime.h>
#include <hip/hip_bf16.h>

typedef __attribute__((ext_vector_type(8))) short short8;
typedef __attribute__((ext_vector_type(4))) short short4v;
typedef __attribute__((ext_vector_type(4))) float floatx4;

#define NEGVAL (-4294967296.0f)

__device__ __forceinline__ short f2bf(float f) {
    union { float f; unsigned u; } v; v.f = f;
    unsigned r = v.u + 0x7fffu + ((v.u >> 16) & 1u);   // RNE
    return (short)(r >> 16);
}

// global->LDS direct copy, 16B per lane. LDS dest = wave-uniform base + lane*16B.
__device__ __forceinline__ void load_lds16(const void* g, void* l) {
    __builtin_amdgcn_global_load_lds(
        (const __attribute__((address_space(1))) unsigned int*)g,
        (__attribute__((address_space(3))) unsigned int*)l, 16, 0, 0);
}

// ---------------------------------------------------------------------------
// Prep 0: x fp32 -> bf16 (row-major, unchanged layout). 8 elems/thread.
// ---------------------------------------------------------------------------
__global__ __launch_bounds__(256) void convx_kernel(
    const float* __restrict__ x, short* __restrict__ xbf)
{
    size_t i = ((size_t)blockIdx.x * 256 + threadIdx.x) << 3;
    float4 a = *(const float4*)&x[i];
    float4 b = *(const float4*)&x[i + 4];
    short8 s;
    s[0] = f2bf(a.x); s[1] = f2bf(a.y); s[2] = f2bf(a.z); s[3] = f2bf(a.w);
    s[4] = f2bf(b.x); s[5] = f2bf(b.y); s[6] = f2bf(b.z); s[7] = f2bf(b.w);
    *(short8*)&xbf[i] = s;
}

// ---------------------------------------------------------------------------
// Prep 1: W[k][n] fp32 -> W^T[n][k] bf16 for wq,wk,wv (-> wt[3][512][512])
// and wo (-> wot[512][512]). 64x64 tiles via LDS.
// ---------------------------------------------------------------------------
__global__ __launch_bounds__(256) void convw_kernel(
    const float* __restrict__ wq, const float* __restrict__ wk,
    const float* __restrict__ wv, const float* __restrict__ wo,
    short* __restrict__ wt, short* __restrict__ wot)
{
    __shared__ __align__(16) short t[64 * 72];           // [k][n] pitch 72
    const int tid  = threadIdx.x;
    const int mat  = blockIdx.x >> 6;
    const int tile = blockIdx.x & 63;
    const int tn = (tile >> 3) << 6, tk = (tile & 7) << 6;
    const float* W = (mat == 0) ? wq : (mat == 1) ? wk : (mat == 2) ? wv : wo;
    short* dst = (mat < 3) ? (wt + ((size_t)mat << 18)) : wot;

    #pragma unroll
    for (int it = 0; it < 4; ++it) {
        int u = tid + (it << 8);
        int kr = u >> 4, c4 = (u & 15) << 2;
        const float4 a = *(const float4*)&W[(size_t)(tk + kr) * 512 + tn + c4];
        short4v s;
        s[0] = f2bf(a.x); s[1] = f2bf(a.y); s[2] = f2bf(a.z); s[3] = f2bf(a.w);
        *(short4v*)&t[kr * 72 + c4] = s;
    }
    __syncthreads();
    #pragma unroll
    for (int it = 0; it < 2; ++it) {
        int u = tid + (it << 8);
        int nr = u >> 3, kc = (u & 7) << 3;
        short8 s;
        #pragma unroll
        for (int j = 0; j < 8; ++j) s[j] = t[(kc + j) * 72 + nr];
        *(short8*)&dst[(size_t)(tn + nr) * 512 + tk + kc] = s;
    }
}

// ---------------------------------------------------------------------------
// Kernel 1: QKV projection, bf16 in / bf16 out, global_load_lds staging.
// C[16384,1536] = xbf[16384,512] @ W^T + bias, scattered head-major.
// V is written TRANSPOSED: vws[n=(h*16+b)][v][s].
// LDS is linear (pitch 32 shorts); bank spread via XOR of the 16B-chunk index
// with (row>>1)&3 applied on BOTH the global source and the fragment read.
// ---------------------------------------------------------------------------
__global__ __launch_bounds__(256) void qkv_kernel(
    const short* __restrict__ xbf, const short* __restrict__ wt,
    const float* __restrict__ bq, const float* __restrict__ bk,
    const float* __restrict__ bv,
    short* __restrict__ qws, short* __restrict__ kws, short* __restrict__ vws)
{
    __shared__ __align__(16) short lA[128 * 32];
    __shared__ __align__(16) short lB[128 * 32];

    const int tid  = threadIdx.x;
    const int wave = tid >> 6, lane = tid & 63;
    const int g = lane >> 4, l16 = lane & 15;
    const int m0 = blockIdx.x * 128;
    const int c0 = blockIdx.y * 128;
    const int wsel = c0 >> 9;
    const int cmat = c0 & 511;
    const float* bias = (wsel == 0) ? bq : (wsel == 1) ? bk : bv;

    floatx4 acc[4][4];
    #pragma unroll
    for (int i = 0; i < 4; i++)
        #pragma unroll
        for (int j = 0; j < 4; j++) acc[i][j] = (floatx4){0.f, 0.f, 0.f, 0.f};

    const int wm = (wave & 1) * 64, wn = (wave >> 1) * 64;
    const int lrow = lane >> 2, lch = lane & 3;    // 16 rows x 4 chunks / instr
    const int stg = wave << 5;                     // this wave stages 32 rows

    for (int k0 = 0; k0 < 512; k0 += 32) {
        #pragma unroll
        for (int i = 0; i < 2; ++i) {
            int r = stg + (i << 4) + lrow;
            load_lds16(&xbf[(size_t)(m0 + r) * 512 + k0 + ((lch ^ ((r >> 1) & 3)) << 3)],
                       &lA[(stg + (i << 4)) * 32]);
        }
        #pragma unroll
        for (int i = 0; i < 2; ++i) {
            int r = stg + (i << 4) + lrow;
            load_lds16(&wt[((size_t)wsel << 18) + (size_t)(cmat + r) * 512 + k0 +
                           ((lch ^ ((r >> 1) & 3)) << 3)],
                       &lB[(stg + (i << 4)) * 32]);
        }
        __syncthreads();

        short8 af[4], bfr[4];
        #pragma unroll
        for (int i = 0; i < 4; i++) {
            int row = wm + i * 16 + l16;
            af[i] = *(short8*)&lA[row * 32 + (((g << 3)) ^ ((((row) >> 1) & 3) << 3))];
        }
        #pragma unroll
        for (int j = 0; j < 4; j++) {
            int row = wn + j * 16 + l16;
            bfr[j] = *(short8*)&lB[row * 32 + (((g << 3)) ^ ((((row) >> 1) & 3) << 3))];
        }
        #pragma unroll
        for (int i = 0; i < 4; i++)
            #pragma unroll
            for (int j = 0; j < 4; j++)
                acc[i][j] = __builtin_amdgcn_mfma_f32_16x16x32_bf16(af[i], bfr[j], acc[i][j], 0, 0, 0);
        __syncthreads();
    }

    if (wsel < 2) {
        short* dst = wsel ? kws : qws;
        #pragma unroll
        for (int j = 0; j < 4; j++) {
            int cb = cmat + wn + j * 16 + l16;
            float bv_ = bias[cb];
            int h = cb >> 6, qd = cb & 63;
            #pragma unroll
            for (int i = 0; i < 4; i++) {
                #pragma unroll
                for (int r = 0; r < 4; r++) {
                    int m = m0 + wm + i * 16 + (g << 2) + r;
                    int b = m >> 10, s = m & 1023;
                    dst[(((size_t)((h << 4) + b) << 10) + s) * 64 + qd] = f2bf(acc[i][j][r] + bv_);
                }
            }
        }
    } else {
        // V transposed: vws[n][v][s], 4 consecutive s per lane -> 8B stores
        #pragma unroll
        for (int j = 0; j < 4; j++) {
            int cb = cmat + wn + j * 16 + l16;
            float bv_ = bias[cb];
            int h = cb >> 6, qd = cb & 63;
            #pragma unroll
            for (int i = 0; i < 4; i++) {
                int m = m0 + wm + i * 16 + (g << 2);
                int b = m >> 10, s = m & 1023;
                short4v sv;
                #pragma unroll
                for (int r = 0; r < 4; r++) sv[r] = f2bf(acc[i][j][r] + bv_);
                *(short4v*)&vws[(((size_t)((h << 4) + b) << 6) + qd) * 1024 + s] = sv;
            }
        }
    }
}

// ---------------------------------------------------------------------------
// Kernel 2: flash attention. K and V^T staged via global_load_lds into linear
// LDS (pitch 64 shorts) with XOR-chunk swizzle (row&7) -> conflict-free b128
// fragment reads. No in-kernel V transpose (V already [n][v][s] in global).
// ---------------------------------------------------------------------------
__global__ __launch_bounds__(256) void attn_kernel(
    const short* __restrict__ qws, const short* __restrict__ kws,
    const short* __restrict__ vws, const int* __restrict__ pm,
    float* __restrict__ raw, short* __restrict__ attnws)
{
    __shared__ __align__(16) short lK[64 * 64];       // [t][d], swizzled chunks
    __shared__ __align__(16) short lVt[64 * 64];      // [v][t], swizzled chunks
    __shared__ __align__(16) short lP[4][16 * 72];    // per-wave P [row][t]
    __shared__ float lMask[1024];

    const int tid  = threadIdx.x;
    const int wave = tid >> 6, lane = tid & 63;
    const int g = lane >> 4, l16 = lane & 15;
    const int bx = blockIdx.x;      // row tile 0..15
    const int n  = blockIdx.y;      // head-major batch-head 0..127
    const int mb = n >> 3;          // faithful index-mismatch: mask batch = n // H

    for (int i = tid; i < 1024; i += 256) lMask[i] = (float)pm[(mb << 10) + i];

    const int srow = (bx << 6) + (wave << 4) + l16;
    const size_t qbase = (((size_t)n << 10) + srow) * 64;
    short8 qf0 = *(const short8*)&qws[qbase + (g << 3)];
    short8 qf1 = *(const short8*)&qws[qbase + 32 + (g << 3)];

    float m_r[4], l_r[4];
    floatx4 Of[4];
    #pragma unroll
    for (int r = 0; r < 4; r++) { m_r[r] = -INFINITY; l_r[r] = 0.f; }
    #pragma unroll
    for (int v = 0; v < 4; v++) Of[v] = (floatx4){0.f, 0.f, 0.f, 0.f};

    float* rawn = raw + ((size_t)n << 20);
    const int rowbase = (bx << 6) + (wave << 4) + (g << 2);
    const int lrow = lane >> 3, lch = lane & 7;       // 8 rows x 8 chunks / instr
    const int stg = wave << 4;                        // this wave stages 16 rows

    for (int c = 0; c < 16; ++c) {
        const int tc = c << 6;
        #pragma unroll
        for (int i = 0; i < 2; ++i) {
            int r = stg + (i << 3) + lrow;
            load_lds16(&kws[(((size_t)n << 10) + tc + r) * 64 + ((lch ^ (r & 7)) << 3)],
                       &lK[(stg + (i << 3)) * 64]);
        }
        #pragma unroll
        for (int i = 0; i < 2; ++i) {
            int r = stg + (i << 3) + lrow;
            load_lds16(&vws[(((size_t)n << 6) + r) * 1024 + tc + ((lch ^ (r & 7)) << 3)],
                       &lVt[(stg + (i << 3)) * 64]);
        }
        __syncthreads();

        // QK^T for this wave's 16 rows x 64 cols
        floatx4 sc[4];
        #pragma unroll
        for (int nt = 0; nt < 4; ++nt) {
            int rr = nt * 16 + l16;
            int sw = (rr & 7) << 3;
            floatx4 a = (floatx4){0.f, 0.f, 0.f, 0.f};
            short8 b0 = *(short8*)&lK[rr * 64 + ((g << 3) ^ sw)];
            short8 b1 = *(short8*)&lK[rr * 64 + ((32 + (g << 3)) ^ sw)];
            a = __builtin_amdgcn_mfma_f32_16x16x32_bf16(qf0, b0, a, 0, 0, 0);
            a = __builtin_amdgcn_mfma_f32_16x16x32_bf16(qf1, b1, a, 0, 0, 0);
            sc[nt] = a;
        }

        // scale, raw write, mask, online softmax
        float p[4][4];
        float cmax[4] = {-INFINITY, -INFINITY, -INFINITY, -INFINITY};
        #pragma unroll
        for (int nt = 0; nt < 4; ++nt) {
            int col = tc + nt * 16 + l16;
            float mk = lMask[col];
            #pragma unroll
            for (int r = 0; r < 4; r++) {
                float v = sc[nt][r] * 0.125f;
                __builtin_nontemporal_store(v, &rawn[((size_t)(rowbase + r) << 10) + col]);
                float mv = (mk != 0.f) ? v : NEGVAL;
                p[nt][r] = mv;
                cmax[r] = fmaxf(cmax[r], mv);
            }
        }
        #pragma unroll
        for (int off = 1; off < 16; off <<= 1) {
            #pragma unroll
            for (int r = 0; r < 4; r++) cmax[r] = fmaxf(cmax[r], __shfl_xor(cmax[r], off));
        }
        float alpha[4], rs[4];
        #pragma unroll
        for (int r = 0; r < 4; r++) {
            float mn = fmaxf(m_r[r], cmax[r]);
            alpha[r] = __expf(m_r[r] - mn);
            m_r[r] = mn;
            rs[r] = 0.f;
        }
        #pragma unroll
        for (int nt = 0; nt < 4; ++nt) {
            #pragma unroll
            for (int r = 0; r < 4; r++) {
                float e = __expf(p[nt][r] - m_r[r]);
                p[nt][r] = e;
                rs[r] += e;
            }
        }
        #pragma unroll
        for (int off = 1; off < 16; off <<= 1) {
            #pragma unroll
            for (int r = 0; r < 4; r++) rs[r] += __shfl_xor(rs[r], off);
        }
        #pragma unroll
        for (int r = 0; r < 4; r++) l_r[r] = l_r[r] * alpha[r] + rs[r];
        #pragma unroll
        for (int v = 0; v < 4; v++)
            #pragma unroll
            for (int r = 0; r < 4; r++) Of[v][r] *= alpha[r];

        // P -> LDS (per-wave buffer; lgkmcnt ordering only, no barrier needed)
        #pragma unroll
        for (int nt = 0; nt < 4; ++nt)
            #pragma unroll
            for (int r = 0; r < 4; r++)
                lP[wave][((g << 2) + r) * 72 + nt * 16 + l16] = f2bf(p[nt][r]);

        // PV accumulate
        #pragma unroll
        for (int ks = 0; ks < 2; ++ks) {
            short8 pa = *(short8*)&lP[wave][l16 * 72 + ks * 32 + (g << 3)];
            #pragma unroll
            for (int v = 0; v < 4; v++) {
                int vr = v * 16 + l16;
                short8 vb = *(short8*)&lVt[vr * 64 + ((ks * 32 + (g << 3)) ^ ((vr & 7) << 3))];
                Of[v] = __builtin_amdgcn_mfma_f32_16x16x32_bf16(pa, vb, Of[v], 0, 0, 0);
            }
        }
        __syncthreads();
    }

    // epilogue: O / l, store heads layout (B,S,H*V) bf16
    const int h = n >> 4, b = n & 15;
    #pragma unroll
    for (int r = 0; r < 4; r++) {
        int s = (bx << 6) + (wave << 4) + (g << 2) + r;
        float inv = 1.f / l_r[r];
        size_t base = ((size_t)((b << 10) + s)) * 512 + (h << 6);
        #pragma unroll
        for (int v = 0; v < 4; v++)
            attnws[base + v * 16 + l16] = f2bf(Of[v][r] * inv);
    }
}

// ---------------------------------------------------------------------------
// Kernel 3: out = heads[16384,512] @ wo + bo.  A = attnws bf16, B = wot bf16
// (pre-transposed [n][k]). Same staging structure as qkv.
// ---------------------------------------------------------------------------
__global__ __launch_bounds__(256) void outproj_kernel(
    const short* __restrict__ attnws, const short* __restrict__ wot,
    const float* __restrict__ bo, float* __restrict__ out)
{
    __shared__ __align__(16) short lA[128 * 32];
    __shared__ __align__(16) short lB[128 * 32];

    const int tid  = threadIdx.x;
    const int wave = tid >> 6, lane = tid & 63;
    const int g = lane >> 4, l16 = lane & 15;
    const int m0 = blockIdx.x * 128;
    const int c0 = blockIdx.y * 128;

    floatx4 acc[4][4];
    #pragma unroll
    for (int i = 0; i < 4; i++)
        #pragma unroll
        for (int j = 0; j < 4; j++) acc[i][j] = (floatx4){0.f, 0.f, 0.f, 0.f};

    const int wm = (wave & 1) * 64, wn = (wave >> 1) * 64;
    const int lrow = lane >> 2, lch = lane & 3;
    const int stg = wave << 5;

    for (int k0 = 0; k0 < 512; k0 += 32) {
        #pragma unroll
        for (int i = 0; i < 2; ++i) {
            int r = stg + (i << 4) + lrow;
            load_lds16(&attnws[(size_t)(m0 + r) * 512 + k0 + ((lch ^ ((r >> 1) & 3)) << 3)],
                       &lA[(stg + (i << 4)) * 32]);
        }
        #pragma unroll
        for (int i = 0; i < 2; ++i) {
            int r = stg + (i << 4) + lrow;
            load_lds16(&wot[(size_t)(c0 + r) * 512 + k0 + ((lch ^ ((r >> 1) & 3)) << 3)],
                       &lB[(stg + (i << 4)) * 32]);
        }
        __syncthreads();

        short8 af[4], bfr[4];
        #pragma unroll
        for (int i = 0; i < 4; i++) {
            int row = wm + i * 16 + l16;
            af[i] = *(short8*)&lA[row * 32 + ((g << 3) ^ (((row >> 1) & 3) << 3))];
        }
        #pragma unroll
        for (int j = 0; j < 4; j++) {
            int row = wn + j * 16 + l16;
            bfr[j] = *(short8*)&lB[row * 32 + ((g << 3) ^ (((row >> 1) & 3) << 3))];
        }
        #pragma unroll
        for (int i = 0; i < 4; i++)
            #pragma unroll
            for (int j = 0; j < 4; j++)
                acc[i][j] = __builtin_amdgcn_mfma_f32_16x16x32_bf16(af[i], bfr[j], acc[i][j], 0, 0, 0);
        __syncthreads();
    }

    #pragma unroll
    for (int j = 0; j < 4; j++) {
        int cg = c0 + wn + j * 16 + l16;
        float bb = bo[cg];
        #pragma unroll
        for (int i = 0; i < 4; i++) {
            #pragma unroll
            for (int r = 0; r < 4; r++) {
                int m = m0 + wm + i * 16 + (g << 2) + r;
                out[(size_t)m * 512 + cg] = acc[i][j][r] + bb;
            }
        }
    }
}

// ---------------------------------------------------------------------------
extern "C" void kernel_launch(void* const* d_in, const int* in_sizes, int n_in,
                              void* d_out, int out_size, void* d_ws, size_t ws_size,
                              hipStream_t stream) {
    const float* x  = (const float*)d_in[0];
    const int*   pm = (const int*)d_in[1];
    const float* wq = (const float*)d_in[2];
    const float* bq = (const float*)d_in[3];
    const float* wk = (const float*)d_in[4];
    const float* bk = (const float*)d_in[5];
    const float* wv = (const float*)d_in[6];
    const float* bv = (const float*)d_in[7];
    const float* wo = (const float*)d_in[8];
    const float* bo = (const float*)d_in[9];

    float* out = (float*)d_out;
    float* raw = out + (size_t)16 * 1024 * 512;       // raw_score after out

    // workspace layout (66 MiB):
    //   qws/kws: head-major [n][s][d] bf16;  vws: TRANSPOSED [n][v][s] bf16
    //   attnws: heads (B,S,H*V) bf16 -- region doubles as xbf (x in bf16)
    //   (xbf is dead before attn writes attnws; lifetimes are disjoint)
    short* qws    = (short*)d_ws;
    short* kws    = qws + (size_t)128 * 1024 * 64;
    short* vws    = kws + (size_t)128 * 1024 * 64;
    short* attnws = vws + (size_t)128 * 1024 * 64;
    short* xbf    = attnws;                           // alias (disjoint lifetime)
    short* wt     = attnws + (size_t)128 * 1024 * 64; // [3][512][512] bf16
    short* wot    = wt + (size_t)3 * 512 * 512;       // [512][512] bf16

    convx_kernel<<<4096, 256, 0, stream>>>(x, xbf);
    convw_kernel<<<256, 256, 0, stream>>>(wq, wk, wv, wo, wt, wot);
    qkv_kernel<<<dim3(128, 12), 256, 0, stream>>>(xbf, wt, bq, bk, bv, qws, kws, vws);
    attn_kernel<<<dim3(16, 128), 256, 0, stream>>>(qws, kws, vws, pm, raw, attnws);
    outproj_kernel<<<dim3(128, 4), 256, 0, stream>>>(attnws, wot, bo, out);
}